// Round 20
// baseline (57.043 us; speedup 1.0000x reference)
//
#include <hip/hip_runtime.h>

// TMoELayer: B=4,T=4096 -> N=16384 tokens, D_IN=1024, D_OUT=1024, E=8, TOP_K=2, R=16
// out[n][o] = sum_k (gate(n,e)*ce[n][r]) * routed[e][o][r], k = e*16+r
// Router logits via split-precision MFMA: W = Whi + Wlo/1024 (f16 pair),
// X = Xhi + Xlo (f16 pair) -> logit = Whi.Xhi + Whi.Xlo + (Wlo.Xhi + Wlo.Xlo)/1024.
// WAVE-INDEPENDENT FUSION: 1 wave per block (64 thr, grid ntok/8). Wave does
// phase A (router+ce, R13 math) then phase B (its 8 tokens x all 1024 o) with
// ZERO barriers anywhere -> waves drift; read-heavy and store-heavy phases
// overlap at wave granularity on each CU.
constexpr float SCALING = 2.0f;  // alpha/r = 32/16

typedef __attribute__((ext_vector_type(8))) _Float16 half8;
typedef __attribute__((ext_vector_type(4))) _Float16 half4;
typedef __attribute__((ext_vector_type(4))) float    f32x4;

// ---------------- Kernel 0: prep (fragment-order tables) — unchanged
__global__ __launch_bounds__(256) void k0_prep(
    const float* __restrict__ routed, const float* __restrict__ compress,
    const float* __restrict__ w_route, _Float16* __restrict__ Btf,
    _Float16* __restrict__ A1f, _Float16* __restrict__ A2f)
{
  const int bid = blockIdx.x, tid = threadIdx.x;
  if (bid < 64){
    const int f = bid * 256 + tid;          // Btf fragment-slot 0..16383
    const int l = f & 63;
    const int rem = f >> 6;
    const int s = rem & 3, ot = rem >> 2;
    const int c15 = l & 15, kg = l >> 4;
    const int e  = 2 * s + (kg >> 1);
    const int r0 = (kg & 1) * 8;
    const float* src = routed + ((size_t)e * 1024 + ot * 16 + c15) * 16 + r0;
    float4 a = *(const float4*)(src);
    float4 b = *(const float4*)(src + 4);
    half8 h;
    h[0]=(_Float16)a.x; h[1]=(_Float16)a.y; h[2]=(_Float16)a.z; h[3]=(_Float16)a.w;
    h[4]=(_Float16)b.x; h[5]=(_Float16)b.y; h[6]=(_Float16)b.z; h[7]=(_Float16)b.w;
    *(half8*)(Btf + (size_t)f * 8) = h;
  } else if (bid < 72){
    const int t2 = (bid - 64) * 256 + tid;  // A2f fragment 0..2047
    const int l = t2 & 63, s = (t2 >> 6) & 7, wq = t2 >> 9;
    const int c15 = l & 15, kg = l >> 4;
    const float* src = compress + (size_t)c15 * 1024 + wq * 256 + s * 32 + kg * 8;
    float4 a = *(const float4*)(src);
    float4 b = *(const float4*)(src + 4);
    half8 h;
    h[0]=(_Float16)(SCALING*a.x); h[1]=(_Float16)(SCALING*a.y);
    h[2]=(_Float16)(SCALING*a.z); h[3]=(_Float16)(SCALING*a.w);
    h[4]=(_Float16)(SCALING*b.x); h[5]=(_Float16)(SCALING*b.y);
    h[6]=(_Float16)(SCALING*b.z); h[7]=(_Float16)(SCALING*b.w);
    *(half8*)(A2f + (size_t)t2 * 8) = h;
  } else {
    const int t3 = (bid - 72) * 256 + tid;  // A1f fragment 0..2047
    const int l = t3 & 63, s = (t3 >> 6) & 7, wq = t3 >> 9;
    const int c15 = l & 15, kg = l >> 4;
    const int row = (c15 < 8) ? c15 : (c15 - 8);
    const float* src = w_route + (size_t)row * 1024 + wq * 256 + s * 32 + kg * 8;
    float4 a = *(const float4*)(src);
    float4 b = *(const float4*)(src + 4);
    float ws[8] = {a.x, a.y, a.z, a.w, b.x, b.y, b.z, b.w};
    half8 h;
    #pragma unroll
    for (int j = 0; j < 8; ++j){
      _Float16 hi = (_Float16)ws[j];
      h[j] = (c15 < 8) ? hi : (_Float16)((ws[j] - (float)hi) * 1024.f);
    }
    *(half8*)(A1f + (size_t)t3 * 8) = h;
  }
}

// ---------------- Fused kernel: ONE WAVE per block, 8 tokens, zero barriers.
__global__ __launch_bounds__(64) void k_fused(
    const float* __restrict__ x, const _Float16* __restrict__ A1f,
    const _Float16* __restrict__ A2f, const _Float16* __restrict__ Btf,
    float* __restrict__ out, int ntok)
{
  __shared__ float buf[4][8][36];       // 4.6 KB wave-private x staging (R13 layout)
  __shared__ _Float16 ce_lds[8][16];    // 256 B wave-private ce bounce

  const int lane = threadIdx.x;         // 0..63
  const int c15 = lane & 15, kg = lane >> 4;
  const int t8 = lane >> 3, d8 = lane & 7;
  const int n0w = blockIdx.x * 8;       // this wave's 8 tokens
  const int tok = c15 & 7;

  // ======== phase A: router + ce (R13 math, wave-local) ========
  f32x4 acc1 = {0.f,0.f,0.f,0.f};   // [Whi;Wlo] * Xhi
  f32x4 acc3 = {0.f,0.f,0.f,0.f};   // [Whi;Wlo] * Xlo
  f32x4 acc2 = {0.f,0.f,0.f,0.f};   // (2*compress) * Xhi
  {
    const float* xw = x + (size_t)(n0w + t8) * 1024 + d8 * 4;
    float4 xg[2][4];
    #pragma unroll
    for (int s = 0; s < 4; ++s) xg[0][s] = *(const float4*)(xw + s * 32);
    #pragma unroll
    for (int g = 0; g < 8; ++g){
      const int cur = g & 1;
      if (g < 7){
        #pragma unroll
        for (int s = 0; s < 4; ++s)
          xg[cur ^ 1][s] = *(const float4*)(xw + (g + 1) * 128 + s * 32);
      }
      #pragma unroll
      for (int s = 0; s < 4; ++s){
        const int ks = g * 4 + s;
        *(f32x4*)&buf[s][t8][d8 * 4] =
            (f32x4){xg[cur][s].x, xg[cur][s].y, xg[cur][s].z, xg[cur][s].w};
        half8 a1 = *(const half8*)(A1f + ((size_t)ks * 64 + lane) * 8);
        half8 a2 = *(const half8*)(A2f + ((size_t)ks * 64 + lane) * 8);
        f32x4 f0 = *(const f32x4*)&buf[s][tok][kg * 8];
        f32x4 f1 = *(const f32x4*)&buf[s][tok][kg * 8 + 4];
        float xs[8] = {f0[0], f0[1], f0[2], f0[3], f1[0], f1[1], f1[2], f1[3]};
        half8 bhi, blo;
        #pragma unroll
        for (int q = 0; q < 8; ++q){
          _Float16 h = (_Float16)xs[q];
          bhi[q] = h;
          blo[q] = (_Float16)(xs[q] - (float)h);
        }
        acc1 = __builtin_amdgcn_mfma_f32_16x16x32_f16(a1, bhi, acc1, 0, 0, 0);
        acc3 = __builtin_amdgcn_mfma_f32_16x16x32_f16(a1, blo, acc3, 0, 0, 0);
        acc2 = __builtin_amdgcn_mfma_f32_16x16x32_f16(a2, bhi, acc2, 0, 0, 0);
      }
    }
  }

  // ---- ce -> wave-private LDS (same-wave DS pipe is in-order; no barrier)
  if (c15 < 8){
    half4 hce;
    hce[0]=(_Float16)acc2[0]; hce[1]=(_Float16)acc2[1];
    hce[2]=(_Float16)acc2[2]; hce[3]=(_Float16)acc2[3];
    *(half4*)&ce_lds[c15][kg * 4] = hce;
  }

  // ---- logits + top-2 + softmax (computed on all lanes; lanes 0-7 authoritative)
  int ge0, ge1; float gw0, gw1;
  {
    float lg[4];
    #pragma unroll
    for (int v = 0; v < 4; ++v){
      float wlo_xhi = __shfl_xor(acc1[v], 32, 64);
      float wlo_xlo = __shfl_xor(acc3[v], 32, 64);
      lg[v] = acc1[v] + acc3[v] + (wlo_xhi + wlo_xlo) * (1.0f / 1024.0f);
    }
    float l8[8];
    #pragma unroll
    for (int v = 0; v < 4; ++v){
      l8[v]     = lg[v];
      l8[4 + v] = __shfl_xor(lg[v], 16, 64);
    }
    float v0 = l8[0]; int e0 = 0;
    #pragma unroll
    for (int e = 1; e < 8; ++e) if (l8[e] > v0){ v0 = l8[e]; e0 = e; }
    float v1 = -3.402823466e38f; int e1 = 0;
    #pragma unroll
    for (int e = 0; e < 8; ++e) if (e != e0 && l8[e] > v1){ v1 = l8[e]; e1 = e; }
    float ex  = __expf(v1 - v0);
    float inv = 1.0f / (1.0f + ex);
    // broadcast token tok's gate from lane tok (lanes 0..7 hold tokens 0..7)
    ge0 = __shfl(e0, tok, 64);
    ge1 = __shfl(e1, tok, 64);
    gw0 = __shfl(inv, tok, 64);
    gw1 = __shfl(ex * inv, tok, 64);
  }

  // ---- build gated-ce B fragments (reused for all 64 o-tiles)
  half8 ce8 = *(const half8*)&ce_lds[tok][(kg & 1) * 8];
  const int eb = kg >> 1;
  half8 bfr[4];
  #pragma unroll
  for (int s = 0; s < 4; ++s){
    const int e = 2 * s + eb;               // expert of k-range [s*32+kg*8, +8)
    float sc = (e == ge0) ? gw0 : ((e == ge1) ? gw1 : 0.f);
    _Float16 sh = (_Float16)sc;
    #pragma unroll
    for (int q = 0; q < 8; ++q) bfr[s][q] = ce8[q] * sh;
  }

  // ======== phase B: out[8 tok][1024 o], 64 o-tiles, zero LDS, zero barriers ====
  #pragma unroll 4
  for (int ot = 0; ot < 64; ++ot){
    f32x4 acc = {0.f, 0.f, 0.f, 0.f};
    #pragma unroll
    for (int s = 0; s < 4; ++s){
      half8 bt = *(const half8*)(Btf + ((size_t)(ot * 4 + s) * 64 + lane) * 8);
      acc = __builtin_amdgcn_mfma_f32_16x16x32_f16(bt, bfr[s], acc, 0, 0, 0);
    }
    // D: col = token (c15, cols 8-15 duplicates), row = o-local = kg*4+v
    if (c15 < 8){
      float4 v = make_float4(acc[0], acc[1], acc[2], acc[3]);
      *(float4*)(out + (size_t)(n0w + c15) * 1024 + ot * 16 + kg * 4) = v;
    }
  }
}

extern "C" void kernel_launch(void* const* d_in, const int* in_sizes, int n_in,
                              void* d_out, int out_size, void* d_ws, size_t ws_size,
                              hipStream_t stream)
{
  const float* x        = (const float*)d_in[0];
  const float* w_route  = (const float*)d_in[1];
  const float* compress = (const float*)d_in[2];
  const float* routed   = (const float*)d_in[3];
  float* out = (float*)d_out;

  const int ntok = in_sizes[0] / 1024;   // 16384 (B*T)
  char* ws = (char*)d_ws;
  _Float16* Btf = (_Float16*)ws;                   // 1024*128 f16 (256 KB)
  _Float16* A1f = (_Float16*)(ws + 262144);        // 16*1024 f16  (32 KB)
  _Float16* A2f = (_Float16*)(ws + 262144 + 32768);// 16*1024 f16  (32 KB)

  k0_prep<<<80, 256, 0, stream>>>(routed, compress, w_route, Btf, A1f, A2f);
  k_fused<<<ntok / 8, 64, 0, stream>>>(x, A1f, A2f, Btf, out, ntok);
}

// Round 21
// 36.784 us; speedup vs baseline: 1.5507x; 1.5507x over previous
//
#include <hip/hip_runtime.h>

// TMoELayer: B=4,T=4096 -> N=16384 tokens, D_IN=1024, D_OUT=1024, E=8, TOP_K=2, R=16
// out[n][o] = sum_k (gate(n,e)*ce[n][r]) * routed[e][o][r], k = e*16+r
// Router logits via split-precision MFMA: W = Whi + Wlo/1024 (f16 pair),
// X = Xhi + Xlo (f16 pair) -> logit = Whi.Xhi + Whi.Xlo + (Wlo.Xhi + Wlo.Xlo)/1024.
// FUSED (R13, best measured 36.8us): 32-token blocks, grid 512.
// Phase A: wave-independent router+ce (8 tok/wave, zero barriers) -> LDS ->
// one barrier -> phase B combine (register Bt fragments, LDS-transpose stores).
constexpr float SCALING = 2.0f;  // alpha/r = 32/16

typedef __attribute__((ext_vector_type(8))) _Float16 half8;
typedef __attribute__((ext_vector_type(4))) _Float16 half4;
typedef __attribute__((ext_vector_type(4))) float    f32x4;

// ---------------- Kernel 0: prep (fragment-order tables)
__global__ __launch_bounds__(256) void k0_prep(
    const float* __restrict__ routed, const float* __restrict__ compress,
    const float* __restrict__ w_route, _Float16* __restrict__ Btf,
    _Float16* __restrict__ A1f, _Float16* __restrict__ A2f)
{
  const int bid = blockIdx.x, tid = threadIdx.x;
  if (bid < 64){
    const int f = bid * 256 + tid;          // Btf fragment-slot 0..16383
    const int l = f & 63;
    const int rem = f >> 6;
    const int s = rem & 3, ot = rem >> 2;
    const int c15 = l & 15, kg = l >> 4;
    const int e  = 2 * s + (kg >> 1);
    const int r0 = (kg & 1) * 8;
    const float* src = routed + ((size_t)e * 1024 + ot * 16 + c15) * 16 + r0;
    float4 a = *(const float4*)(src);
    float4 b = *(const float4*)(src + 4);
    half8 h;
    h[0]=(_Float16)a.x; h[1]=(_Float16)a.y; h[2]=(_Float16)a.z; h[3]=(_Float16)a.w;
    h[4]=(_Float16)b.x; h[5]=(_Float16)b.y; h[6]=(_Float16)b.z; h[7]=(_Float16)b.w;
    *(half8*)(Btf + (size_t)f * 8) = h;
  } else if (bid < 72){
    const int t2 = (bid - 64) * 256 + tid;  // A2f fragment 0..2047
    const int l = t2 & 63, s = (t2 >> 6) & 7, wq = t2 >> 9;
    const int c15 = l & 15, kg = l >> 4;
    const float* src = compress + (size_t)c15 * 1024 + wq * 256 + s * 32 + kg * 8;
    float4 a = *(const float4*)(src);
    float4 b = *(const float4*)(src + 4);
    half8 h;
    h[0]=(_Float16)(SCALING*a.x); h[1]=(_Float16)(SCALING*a.y);
    h[2]=(_Float16)(SCALING*a.z); h[3]=(_Float16)(SCALING*a.w);
    h[4]=(_Float16)(SCALING*b.x); h[5]=(_Float16)(SCALING*b.y);
    h[6]=(_Float16)(SCALING*b.z); h[7]=(_Float16)(SCALING*b.w);
    *(half8*)(A2f + (size_t)t2 * 8) = h;
  } else {
    const int t3 = (bid - 72) * 256 + tid;  // A1f fragment 0..2047
    const int l = t3 & 63, s = (t3 >> 6) & 7, wq = t3 >> 9;
    const int c15 = l & 15, kg = l >> 4;
    const int row = (c15 < 8) ? c15 : (c15 - 8);
    const float* src = w_route + (size_t)row * 1024 + wq * 256 + s * 32 + kg * 8;
    float4 a = *(const float4*)(src);
    float4 b = *(const float4*)(src + 4);
    float ws[8] = {a.x, a.y, a.z, a.w, b.x, b.y, b.z, b.w};
    half8 h;
    #pragma unroll
    for (int j = 0; j < 8; ++j){
      _Float16 hi = (_Float16)ws[j];
      h[j] = (c15 < 8) ? hi : (_Float16)((ws[j] - (float)hi) * 1024.f);
    }
    *(half8*)(A1f + (size_t)t3 * 8) = h;
  }
}

// ---------------- Fused kernel: block = 32 tokens, 4 waves, grid 512.
// Phase A: wave = 8 tokens, full K, zero barriers (wave-private LDS staging).
// One __syncthreads. Phase B: per-bn register Bt fragments, per-wave LDS
// transpose for dense 1KB-contiguous stores, no barriers.
__global__ __launch_bounds__(256, 4) void k_fused(
    const float* __restrict__ x, const _Float16* __restrict__ A1f,
    const _Float16* __restrict__ A2f, const _Float16* __restrict__ Btf,
    float* __restrict__ out, int ntok)
{
  __shared__ __align__(16) char smem[34816];   // phase-A buf ALIASES phase-B tbuf
  __shared__ _Float16 ce_lds[32][24];          // 1.5 KB
  __shared__ float    gate_lds[32][5];         // 640 B
  float (*buf)[4][8][36]  = (float(*)[4][8][36])smem;    // [wave][slot][tok][36]
  float (*tbuf)[2][16][68] = (float(*)[2][16][68])smem;  // [wave][dbuf][16][68]

  const int tid = threadIdx.x, lane = tid & 63, wv = tid >> 6;
  const int c15 = lane & 15, kg = lane >> 4;
  const int t8 = lane >> 3, d8 = lane & 7;
  const int n0 = blockIdx.x * 32;
  const int n0w = n0 + wv * 8;                 // this wave's 8 tokens

  // ======== phase A ========
  {
    const float* xw = x + (size_t)(n0w + t8) * 1024 + d8 * 4;
    f32x4 acc1 = {0.f,0.f,0.f,0.f};   // [Whi;Wlo] * Xhi
    f32x4 acc3 = {0.f,0.f,0.f,0.f};   // [Whi;Wlo] * Xlo
    f32x4 acc2 = {0.f,0.f,0.f,0.f};   // (2*compress) * Xhi
    float4 xg[2][4];
    #pragma unroll
    for (int s = 0; s < 4; ++s) xg[0][s] = *(const float4*)(xw + s * 32);
    #pragma unroll
    for (int g = 0; g < 8; ++g){
      const int cur = g & 1;
      if (g < 7){
        #pragma unroll
        for (int s = 0; s < 4; ++s)
          xg[cur ^ 1][s] = *(const float4*)(xw + (g + 1) * 128 + s * 32);
      }
      #pragma unroll
      for (int s = 0; s < 4; ++s){
        const int ks = g * 4 + s;
        *(f32x4*)&buf[wv][s][t8][d8 * 4] =
            (f32x4){xg[cur][s].x, xg[cur][s].y, xg[cur][s].z, xg[cur][s].w};
        half8 a1 = *(const half8*)(A1f + ((size_t)ks * 64 + lane) * 8);
        half8 a2 = *(const half8*)(A2f + ((size_t)ks * 64 + lane) * 8);
        f32x4 f0 = *(const f32x4*)&buf[wv][s][c15 & 7][kg * 8];
        f32x4 f1 = *(const f32x4*)&buf[wv][s][c15 & 7][kg * 8 + 4];
        float xs[8] = {f0[0], f0[1], f0[2], f0[3], f1[0], f1[1], f1[2], f1[3]};
        half8 bhi, blo;
        #pragma unroll
        for (int q = 0; q < 8; ++q){
          _Float16 h = (_Float16)xs[q];
          bhi[q] = h;
          blo[q] = (_Float16)(xs[q] - (float)h);
        }
        acc1 = __builtin_amdgcn_mfma_f32_16x16x32_f16(a1, bhi, acc1, 0, 0, 0);
        acc3 = __builtin_amdgcn_mfma_f32_16x16x32_f16(a1, blo, acc3, 0, 0, 0);
        acc2 = __builtin_amdgcn_mfma_f32_16x16x32_f16(a2, bhi, acc2, 0, 0, 0);
      }
    }
    // epilogue -> LDS (block-local rows)
    if (c15 < 8){
      half4 hce;
      hce[0]=(_Float16)acc2[0]; hce[1]=(_Float16)acc2[1];
      hce[2]=(_Float16)acc2[2]; hce[3]=(_Float16)acc2[3];
      *(half4*)&ce_lds[wv * 8 + c15][kg * 4] = hce;
    }
    float lg[4];
    #pragma unroll
    for (int v = 0; v < 4; ++v){
      float wlo_xhi = __shfl_xor(acc1[v], 32, 64);
      float wlo_xlo = __shfl_xor(acc3[v], 32, 64);
      lg[v] = acc1[v] + acc3[v] + (wlo_xhi + wlo_xlo) * (1.0f / 1024.0f);
    }
    float l8[8];
    #pragma unroll
    for (int v = 0; v < 4; ++v){
      l8[v]     = lg[v];
      l8[4 + v] = __shfl_xor(lg[v], 16, 64);
    }
    if (lane < 8){
      float v0 = l8[0]; int e0 = 0;
      #pragma unroll
      for (int e = 1; e < 8; ++e) if (l8[e] > v0){ v0 = l8[e]; e0 = e; }
      float v1 = -3.402823466e38f; int e1 = 0;
      #pragma unroll
      for (int e = 0; e < 8; ++e) if (e != e0 && l8[e] > v1){ v1 = l8[e]; e1 = e; }
      float ex  = __expf(v1 - v0);
      float inv = 1.0f / (1.0f + ex);
      gate_lds[wv * 8 + lane][0] = __int_as_float(e0);
      gate_lds[wv * 8 + lane][1] = __int_as_float(e1);
      gate_lds[wv * 8 + lane][2] = inv;
      gate_lds[wv * 8 + lane][3] = ex * inv;
    }
  }
  __syncthreads();   // ce/gate published; phase-A buf dead -> tbuf may reuse smem

  // ======== phase B: out[32 tok][1024 o] over 4 o-chunks ========
  #pragma unroll 1
  for (int bn = 0; bn < 4; ++bn){
    const int o0w = bn * 256 + wv * 64;
    half8 bt[4][4];
    #pragma unroll
    for (int nc = 0; nc < 4; ++nc){
      const int ot = bn * 16 + wv * 4 + nc;
      #pragma unroll
      for (int s = 0; s < 4; ++s)
        bt[nc][s] = *(const half8*)(Btf + ((size_t)(ot * 4 + s) * 64 + lane) * 8);
    }
    #pragma unroll
    for (int i = 0; i < 2; ++i){
      const int tl = i * 16 + c15;                  // block-local token
      half8 ce_c = *(const half8*)&ce_lds[tl][(kg & 1) * 8];
      const int e0 = __float_as_int(gate_lds[tl][0]);
      const int e1 = __float_as_int(gate_lds[tl][1]);
      const float w0 = gate_lds[tl][2], w1 = gate_lds[tl][3];
      const int eb = kg >> 1;

      f32x4 acc[4] = {{0.f,0.f,0.f,0.f},{0.f,0.f,0.f,0.f},
                      {0.f,0.f,0.f,0.f},{0.f,0.f,0.f,0.f}};
      #pragma unroll
      for (int s = 0; s < 4; ++s){
        const int e = 2 * s + eb;          // expert of k-range [s*32+kg*8, +8)
        float sc = (e == e0) ? w0 : ((e == e1) ? w1 : 0.f);
        _Float16 sh = (_Float16)sc;
        half8 bfr;
        #pragma unroll
        for (int q = 0; q < 8; ++q) bfr[q] = ce_c[q] * sh;
        #pragma unroll
        for (int nc = 0; nc < 4; ++nc)
          acc[nc] = __builtin_amdgcn_mfma_f32_16x16x32_f16(bt[nc][s], bfr, acc[nc], 0, 0, 0);
      }
      const int db = (bn * 2 + i) & 1;
      #pragma unroll
      for (int nc = 0; nc < 4; ++nc)
        *(f32x4*)&tbuf[wv][db][c15][nc * 16 + kg * 4] = acc[nc];
      // per-wave in-order DS pipe: reads below wait via lgkmcnt, no barrier.
      const int n0i = n0 + i * 16;
      #pragma unroll
      for (int p = 0; p < 4; ++p){
        const int row = p * 4 + kg;        // token-local row
        float4 v = *(const float4*)&tbuf[wv][db][row][c15 * 4];
        *(float4*)(out + (size_t)(n0i + row) * 1024 + o0w + c15 * 4) = v;
      }
    }
  }
}

extern "C" void kernel_launch(void* const* d_in, const int* in_sizes, int n_in,
                              void* d_out, int out_size, void* d_ws, size_t ws_size,
                              hipStream_t stream)
{
  const float* x        = (const float*)d_in[0];
  const float* w_route  = (const float*)d_in[1];
  const float* compress = (const float*)d_in[2];
  const float* routed   = (const float*)d_in[3];
  float* out = (float*)d_out;

  const int ntok = in_sizes[0] / 1024;   // 16384 (B*T)
  char* ws = (char*)d_ws;
  _Float16* Btf = (_Float16*)ws;                   // 1024*128 f16 (256 KB)
  _Float16* A1f = (_Float16*)(ws + 262144);        // 16*1024 f16  (32 KB)
  _Float16* A2f = (_Float16*)(ws + 262144 + 32768);// 16*1024 f16  (32 KB)

  k0_prep<<<80, 256, 0, stream>>>(routed, compress, w_route, Btf, A1f, A2f);
  k_fused<<<ntok / 32, 256, 0, stream>>>(x, A1f, A2f, Btf, out, ntok);
}